// Round 1
// baseline (791.234 us; speedup 1.0000x reference)
//
#include <hip/hip_runtime.h>

#define N_NODES 50000
#define N_EDGES 800000
#define C 64          // channels (C_IN == C_HID == 64)

// ---------------------------------------------------------------------------
// Kernel 1: per-node transform. h = x @ W  (to ws), r = x @ root + bias (to out).
// One wave (64 lanes) per node; lane c owns output channel c.
// W and root staged in LDS; x row broadcast across lanes via __shfl.
// ---------------------------------------------------------------------------
__global__ __launch_bounds__(256) void node_transform(
    const float* __restrict__ x,
    const float* __restrict__ W,
    const float* __restrict__ R,
    const float* __restrict__ bias,
    float* __restrict__ h,
    float* __restrict__ r_out)
{
    __shared__ float Ws[C][C];
    __shared__ float Rs[C][C];
    for (int i = threadIdx.x; i < C * C; i += blockDim.x) {
        Ws[i >> 6][i & 63] = W[i];
        Rs[i >> 6][i & 63] = R[i];
    }
    __syncthreads();

    const int lane = threadIdx.x & 63;
    const int wid  = threadIdx.x >> 6;
    const int wavesPerBlock = blockDim.x >> 6;
    const int nWaves = gridDim.x * wavesPerBlock;
    const float b = bias[lane];

    for (int n = blockIdx.x * wavesPerBlock + wid; n < N_NODES; n += nWaves) {
        const float xv = x[n * C + lane];   // lane k holds x[n][k]
        float acc_h = 0.0f, acc_r = 0.0f;
        #pragma unroll
        for (int k = 0; k < C; ++k) {
            const float xk = __shfl(xv, k);
            acc_h = fmaf(xk, Ws[k][lane], acc_h);
            acc_r = fmaf(xk, Rs[k][lane], acc_r);
        }
        h[n * C + lane]     = acc_h;
        r_out[n * C + lane] = acc_r + b;    // bias folded in here
    }
}

// ---------------------------------------------------------------------------
// Kernel 2: edge scatter. 16 threads per edge; each thread handles 4 channels.
// msg[dst] += h[src]; deg[dst] += 1 (lane 0 of each 16-group).
// ---------------------------------------------------------------------------
__global__ __launch_bounds__(256) void scatter_edges(
    const int* __restrict__ ei,          // [2, N_EDGES] row-major
    const float* __restrict__ h,
    float* __restrict__ msg,
    float* __restrict__ deg)
{
    const long long total = (long long)N_EDGES * 16;
    const long long stride = (long long)gridDim.x * blockDim.x;
    for (long long t = (long long)blockIdx.x * blockDim.x + threadIdx.x;
         t < total; t += stride) {
        const int e  = (int)(t >> 4);
        const int c4 = ((int)t & 15) << 2;
        const int src = ei[e];
        const int dst = ei[N_EDGES + e];
        const float4 hv = *reinterpret_cast<const float4*>(&h[src * C + c4]);
        float* m = &msg[dst * C + c4];
        atomicAdd(m + 0, hv.x);
        atomicAdd(m + 1, hv.y);
        atomicAdd(m + 2, hv.z);
        atomicAdd(m + 3, hv.w);
        if ((t & 15) == 0) atomicAdd(&deg[dst], 1.0f);
    }
}

// ---------------------------------------------------------------------------
// Kernel 3: finalize. out = relu(out + msg / max(deg,1)).  float4 streaming.
// ---------------------------------------------------------------------------
__global__ __launch_bounds__(256) void finalize(
    const float* __restrict__ msg,
    const float* __restrict__ deg,
    float* __restrict__ out)
{
    const int total4 = N_NODES * (C / 4);           // 800000 float4 elements
    const int stride = gridDim.x * blockDim.x;
    for (int i = blockIdx.x * blockDim.x + threadIdx.x; i < total4; i += stride) {
        const int n = i >> 4;                        // 16 float4 per node row
        const float d   = fmaxf(deg[n], 1.0f);
        const float inv = 1.0f / d;
        const float4 m = reinterpret_cast<const float4*>(msg)[i];
        float4 o = reinterpret_cast<float4*>(out)[i];
        o.x = fmaxf(fmaf(m.x, inv, o.x), 0.0f);
        o.y = fmaxf(fmaf(m.y, inv, o.y), 0.0f);
        o.z = fmaxf(fmaf(m.z, inv, o.z), 0.0f);
        o.w = fmaxf(fmaf(m.w, inv, o.w), 0.0f);
        reinterpret_cast<float4*>(out)[i] = o;
    }
}

// ---------------------------------------------------------------------------
// Launch. Inputs: x[3.2M f32], edge_index[1.6M i32], edge_attr[800k f32 unused],
// W[4096 f32], root[4096 f32], bias[64 f32]. Output: 3.2M f32.
// ws layout: h at [0, 3.2M), msg at [3.2M, 6.4M), deg at [6.4M, 6.45M) floats.
// ---------------------------------------------------------------------------
extern "C" void kernel_launch(void* const* d_in, const int* in_sizes, int n_in,
                              void* d_out, int out_size, void* d_ws, size_t ws_size,
                              hipStream_t stream)
{
    const float* x    = (const float*)d_in[0];
    const int*   ei   = (const int*)d_in[1];
    // d_in[2] = edge_attr: drops out for kernel_size=1 SplineConv
    const float* W    = (const float*)d_in[3];
    const float* R    = (const float*)d_in[4];
    const float* bias = (const float*)d_in[5];

    float* ws  = (float*)d_ws;
    float* h   = ws;                       // 3,200,000 floats
    float* msg = ws + (size_t)N_NODES * C; // 3,200,000 floats
    float* deg = msg + (size_t)N_NODES * C;// 50,000 floats
    float* out = (float*)d_out;

    // zero msg + deg (contiguous)
    hipMemsetAsync(msg, 0, ((size_t)N_NODES * C + N_NODES) * sizeof(float), stream);

    node_transform<<<2048, 256, 0, stream>>>(x, W, R, bias, h, out);
    scatter_edges<<<4096, 256, 0, stream>>>(ei, h, msg, deg);
    finalize<<<3125, 256, 0, stream>>>(msg, deg, out);
}

// Round 2
// 288.168 us; speedup vs baseline: 2.7457x; 2.7457x over previous
//
#include <hip/hip_runtime.h>

#define N_NODES 50000
#define N_EDGES 800000
#define C 64          // channels (C_IN == C_HID == 64)

// ---------------------------------------------------------------------------
// Kernel 1: per-node transform. h = x @ W  (to ws), r = x @ root + bias (to out).
// One wave (64 lanes) per node; lane c owns output channel c.
// ---------------------------------------------------------------------------
__global__ __launch_bounds__(256) void node_transform(
    const float* __restrict__ x,
    const float* __restrict__ W,
    const float* __restrict__ R,
    const float* __restrict__ bias,
    float* __restrict__ h,
    float* __restrict__ r_out)
{
    __shared__ float Ws[C][C];
    __shared__ float Rs[C][C];
    for (int i = threadIdx.x; i < C * C; i += blockDim.x) {
        Ws[i >> 6][i & 63] = W[i];
        Rs[i >> 6][i & 63] = R[i];
    }
    __syncthreads();

    const int lane = threadIdx.x & 63;
    const int wid  = threadIdx.x >> 6;
    const int wavesPerBlock = blockDim.x >> 6;
    const int nWaves = gridDim.x * wavesPerBlock;
    const float b = bias[lane];

    for (int n = blockIdx.x * wavesPerBlock + wid; n < N_NODES; n += nWaves) {
        const float xv = x[n * C + lane];   // lane k holds x[n][k]
        float acc_h = 0.0f, acc_r = 0.0f;
        #pragma unroll
        for (int k = 0; k < C; ++k) {
            const float xk = __shfl(xv, k);
            acc_h = fmaf(xk, Ws[k][lane], acc_h);
            acc_r = fmaf(xk, Rs[k][lane], acc_r);
        }
        h[n * C + lane]     = acc_h;
        r_out[n * C + lane] = acc_r + b;    // bias folded in
    }
}

// ---------------------------------------------------------------------------
// Kernel 2: degree histogram (int atomics, L2-resident).
// ---------------------------------------------------------------------------
__global__ __launch_bounds__(256) void count_deg(
    const int* __restrict__ ei, int* __restrict__ deg)
{
    const int stride = gridDim.x * blockDim.x;
    for (int e = blockIdx.x * blockDim.x + threadIdx.x; e < N_EDGES; e += stride)
        atomicAdd(&deg[ei[N_EDGES + e]], 1);
}

// ---------------------------------------------------------------------------
// Kernel 3: exclusive prefix sum over 50k degrees. Single workgroup of 1024.
// Writes rowptr[0..N] and cursor[0..N-1] (= rowptr copy for placement).
// ---------------------------------------------------------------------------
__global__ __launch_bounds__(1024) void scan_deg(
    const int* __restrict__ deg, int* __restrict__ rowptr, int* __restrict__ cursor)
{
    __shared__ int part[1024];
    const int t = threadIdx.x;
    const int CHUNK = (N_NODES + 1023) / 1024;   // 49
    const int beg = t * CHUNK;
    const int end = min(beg + CHUNK, N_NODES);

    int s = 0;
    for (int i = beg; i < end; ++i) s += deg[i];
    part[t] = s;
    __syncthreads();
    for (int off = 1; off < 1024; off <<= 1) {   // inclusive Hillis-Steele
        int v = (t >= off) ? part[t - off] : 0;
        __syncthreads();
        part[t] += v;
        __syncthreads();
    }
    int run = (t == 0) ? 0 : part[t - 1];
    for (int i = beg; i < end; ++i) {
        rowptr[i] = run;
        cursor[i] = run;
        run += deg[i];
    }
    if (t == 1023) rowptr[N_NODES] = part[1023];
}

// ---------------------------------------------------------------------------
// Kernel 4: place each edge's src id into its destination's CSR segment.
// ---------------------------------------------------------------------------
__global__ __launch_bounds__(256) void build_csr(
    const int* __restrict__ ei, int* __restrict__ cursor, int* __restrict__ ebuf)
{
    const int stride = gridDim.x * blockDim.x;
    for (int e = blockIdx.x * blockDim.x + threadIdx.x; e < N_EDGES; e += stride) {
        const int dst = ei[N_EDGES + e];
        const int pos = atomicAdd(&cursor[dst], 1);
        ebuf[pos] = ei[e];                       // src
    }
}

// ---------------------------------------------------------------------------
// Kernel 5: gather-aggregate + finalize. One wave per node, lane c = channel c.
// out = relu( sum_{j in N(i)} h[j] / max(deg,1) + out )   (out holds x@root+b)
// ---------------------------------------------------------------------------
__global__ __launch_bounds__(256) void aggregate(
    const int* __restrict__ rowptr,
    const int* __restrict__ ebuf,
    const float* __restrict__ h,
    float* __restrict__ out)
{
    const int lane = threadIdx.x & 63;
    const int wid  = threadIdx.x >> 6;
    const int n    = blockIdx.x * 4 + wid;       // 4 waves per block
    if (n >= N_NODES) return;

    const int beg = rowptr[n];
    const int end = rowptr[n + 1];

    float acc = 0.0f;
    for (int base = beg; base < end; base += 64) {
        const int m = min(64, end - base);
        const int sid = (base + lane < end) ? ebuf[base + lane] : 0;
        int j = 0;
        for (; j + 4 <= m; j += 4) {             // 4-wide ILP on the gathers
            const int s0 = __shfl(sid, j + 0);
            const int s1 = __shfl(sid, j + 1);
            const int s2 = __shfl(sid, j + 2);
            const int s3 = __shfl(sid, j + 3);
            const float v0 = h[s0 * C + lane];
            const float v1 = h[s1 * C + lane];
            const float v2 = h[s2 * C + lane];
            const float v3 = h[s3 * C + lane];
            acc += (v0 + v1) + (v2 + v3);
        }
        for (; j < m; ++j) {
            const int s = __shfl(sid, j);
            acc += h[s * C + lane];
        }
    }

    const float d   = (float)(end - beg);
    const float inv = 1.0f / fmaxf(d, 1.0f);
    const float o   = fmaf(acc, inv, out[n * C + lane]);
    out[n * C + lane] = fmaxf(o, 0.0f);
}

// ---------------------------------------------------------------------------
// Launch. ws layout (16B-aligned regions):
//   h      : float[3,200,000]                (12.8 MB)
//   deg    : int[50,000]
//   rowptr : int[50,001]
//   cursor : int[50,000]
//   ebuf   : int[800,000]
// ---------------------------------------------------------------------------
extern "C" void kernel_launch(void* const* d_in, const int* in_sizes, int n_in,
                              void* d_out, int out_size, void* d_ws, size_t ws_size,
                              hipStream_t stream)
{
    const float* x    = (const float*)d_in[0];
    const int*   ei   = (const int*)d_in[1];
    // d_in[2] = edge_attr: drops out for kernel_size=1 SplineConv
    const float* W    = (const float*)d_in[3];
    const float* R    = (const float*)d_in[4];
    const float* bias = (const float*)d_in[5];

    char* wsb = (char*)d_ws;
    float* h      = (float*)wsb;
    size_t off    = (size_t)N_NODES * C * sizeof(float);
    int*   deg    = (int*)(wsb + off);            off += ((N_NODES + 3) & ~3) * sizeof(int);
    int*   rowptr = (int*)(wsb + off);            off += ((N_NODES + 1 + 3) & ~3) * sizeof(int);
    int*   cursor = (int*)(wsb + off);            off += ((N_NODES + 3) & ~3) * sizeof(int);
    int*   ebuf   = (int*)(wsb + off);
    float* out    = (float*)d_out;

    hipMemsetAsync(deg, 0, N_NODES * sizeof(int), stream);

    node_transform<<<2048, 256, 0, stream>>>(x, W, R, bias, h, out);
    count_deg    <<<2048, 256, 0, stream>>>(ei, deg);
    scan_deg     <<<1, 1024, 0, stream>>>(deg, rowptr, cursor);
    build_csr    <<<2048, 256, 0, stream>>>(ei, cursor, ebuf);
    aggregate    <<<(N_NODES + 3) / 4, 256, 0, stream>>>(rowptr, ebuf, h, out);
}

// Round 3
// 185.140 us; speedup vs baseline: 4.2737x; 1.5565x over previous
//
#include <hip/hip_runtime.h>

#define N_NODES 50000
#define N_EDGES 800000
#define C 64                         // channels (C_IN == C_HID == 64)
#define NB 256                       // nodes per scan block
#define NBLK ((N_NODES + NB - 1) / NB)   // 196 scan blocks

// ---------------------------------------------------------------------------
// Kernel 1: per-node transform. h = x @ W  (to ws), r = x @ root + bias (to out).
// One wave (64 lanes) per node; lane c owns output channel c.
// ---------------------------------------------------------------------------
__global__ __launch_bounds__(256) void node_transform(
    const float* __restrict__ x,
    const float* __restrict__ W,
    const float* __restrict__ R,
    const float* __restrict__ bias,
    float* __restrict__ h,
    float* __restrict__ r_out)
{
    __shared__ float Ws[C][C];
    __shared__ float Rs[C][C];
    for (int i = threadIdx.x; i < C * C; i += blockDim.x) {
        Ws[i >> 6][i & 63] = W[i];
        Rs[i >> 6][i & 63] = R[i];
    }
    __syncthreads();

    const int lane = threadIdx.x & 63;
    const int wid  = threadIdx.x >> 6;
    const int wavesPerBlock = blockDim.x >> 6;
    const int nWaves = gridDim.x * wavesPerBlock;
    const float b = bias[lane];

    for (int n = blockIdx.x * wavesPerBlock + wid; n < N_NODES; n += nWaves) {
        const float xv = x[n * C + lane];
        float acc_h = 0.0f, acc_r = 0.0f;
        #pragma unroll
        for (int k = 0; k < C; ++k) {
            const float xk = __shfl(xv, k);
            acc_h = fmaf(xk, Ws[k][lane], acc_h);
            acc_r = fmaf(xk, Rs[k][lane], acc_r);
        }
        h[n * C + lane]     = acc_h;
        r_out[n * C + lane] = acc_r + b;    // bias folded in
    }
}

// ---------------------------------------------------------------------------
// Kernel 2: degree histogram (int atomics, L2-resident).
// ---------------------------------------------------------------------------
__global__ __launch_bounds__(256) void count_deg(
    const int* __restrict__ ei, int* __restrict__ deg)
{
    const int stride = gridDim.x * blockDim.x;
    for (int e = blockIdx.x * blockDim.x + threadIdx.x; e < N_EDGES; e += stride)
        atomicAdd(&deg[ei[N_EDGES + e]], 1);
}

// ---------------------------------------------------------------------------
// Kernel 3a: per-block degree sums.
// ---------------------------------------------------------------------------
__global__ __launch_bounds__(256) void block_sums(
    const int* __restrict__ deg, int* __restrict__ partial)
{
    const int i = blockIdx.x * NB + threadIdx.x;
    int v = (i < N_NODES) ? deg[i] : 0;
    #pragma unroll
    for (int off = 32; off; off >>= 1) v += __shfl_down(v, off);
    __shared__ int ws4[4];
    if ((threadIdx.x & 63) == 0) ws4[threadIdx.x >> 6] = v;
    __syncthreads();
    if (threadIdx.x == 0)
        partial[blockIdx.x] = ws4[0] + ws4[1] + ws4[2] + ws4[3];
}

// ---------------------------------------------------------------------------
// Kernel 3b: exclusive scan of the 196 block partials. Single wave.
// ---------------------------------------------------------------------------
__global__ __launch_bounds__(64) void scan_partials(
    const int* __restrict__ partial, int* __restrict__ blockoff)
{
    const int lane = threadIdx.x;          // 0..63, 4 partials per lane
    const int base = lane * 4;
    int s0 = (base + 0 < NBLK) ? partial[base + 0] : 0;
    int s1 = (base + 1 < NBLK) ? partial[base + 1] : 0;
    int s2 = (base + 2 < NBLK) ? partial[base + 2] : 0;
    int s3 = (base + 3 < NBLK) ? partial[base + 3] : 0;
    const int tot = s0 + s1 + s2 + s3;
    int incl = tot;
    #pragma unroll
    for (int off = 1; off < 64; off <<= 1) {
        const int t = __shfl_up(incl, off);
        if (lane >= off) incl += t;
    }
    int run = incl - tot;                  // exclusive
    if (base + 0 < NBLK) blockoff[base + 0] = run;          run += s0;
    if (base + 1 < NBLK) blockoff[base + 1] = run;          run += s1;
    if (base + 2 < NBLK) blockoff[base + 2] = run;          run += s2;
    if (base + 3 < NBLK) blockoff[base + 3] = run;
}

// ---------------------------------------------------------------------------
// Kernel 3c: in-block exclusive scan + block offset -> rowptr, cursor.
// ---------------------------------------------------------------------------
__global__ __launch_bounds__(256) void write_scan(
    const int* __restrict__ deg, const int* __restrict__ blockoff,
    int* __restrict__ rowptr, int* __restrict__ cursor)
{
    const int i = blockIdx.x * NB + threadIdx.x;
    const int v = (i < N_NODES) ? deg[i] : 0;
    const int lane = threadIdx.x & 63;
    const int w    = threadIdx.x >> 6;
    int incl = v;
    #pragma unroll
    for (int off = 1; off < 64; off <<= 1) {
        const int t = __shfl_up(incl, off);
        if (lane >= off) incl += t;
    }
    __shared__ int wsum[4];
    if (lane == 63) wsum[w] = incl;
    __syncthreads();
    int woff = blockoff[blockIdx.x];
    for (int k = 0; k < 4; ++k) if (k < w) woff += wsum[k];
    const int excl = incl - v + woff;
    if (i < N_NODES) {
        rowptr[i] = excl;
        cursor[i] = excl;
        if (i == N_NODES - 1) rowptr[N_NODES] = excl + v;
    }
}

// ---------------------------------------------------------------------------
// Kernel 4: place each edge's src id into its destination's CSR segment.
// ---------------------------------------------------------------------------
__global__ __launch_bounds__(256) void build_csr(
    const int* __restrict__ ei, int* __restrict__ cursor, int* __restrict__ ebuf)
{
    const int stride = gridDim.x * blockDim.x;
    for (int e = blockIdx.x * blockDim.x + threadIdx.x; e < N_EDGES; e += stride) {
        const int dst = ei[N_EDGES + e];
        const int pos = atomicAdd(&cursor[dst], 1);
        ebuf[pos] = ei[e];                       // src
    }
}

// ---------------------------------------------------------------------------
// Kernel 5: gather-aggregate + finalize. One wave per node, lane c = channel c.
// out = relu( sum_{j in N(i)} h[j] / max(deg,1) + out )   (out holds x@root+b)
// ---------------------------------------------------------------------------
__global__ __launch_bounds__(256) void aggregate(
    const int* __restrict__ rowptr,
    const int* __restrict__ ebuf,
    const float* __restrict__ h,
    float* __restrict__ out)
{
    const int lane = threadIdx.x & 63;
    const int wid  = threadIdx.x >> 6;
    const int n    = blockIdx.x * 4 + wid;       // 4 waves per block
    if (n >= N_NODES) return;

    const int beg = rowptr[n];
    const int end = rowptr[n + 1];

    float acc = 0.0f;
    for (int base = beg; base < end; base += 64) {
        const int m = min(64, end - base);
        const int sid = (base + lane < end) ? ebuf[base + lane] : 0;
        int j = 0;
        for (; j + 4 <= m; j += 4) {
            const int s0 = __shfl(sid, j + 0);
            const int s1 = __shfl(sid, j + 1);
            const int s2 = __shfl(sid, j + 2);
            const int s3 = __shfl(sid, j + 3);
            const float v0 = h[s0 * C + lane];
            const float v1 = h[s1 * C + lane];
            const float v2 = h[s2 * C + lane];
            const float v3 = h[s3 * C + lane];
            acc += (v0 + v1) + (v2 + v3);
        }
        for (; j < m; ++j) {
            const int s = __shfl(sid, j);
            acc += h[s * C + lane];
        }
    }

    const float d   = (float)(end - beg);
    const float inv = 1.0f / fmaxf(d, 1.0f);
    const float o   = fmaf(acc, inv, out[n * C + lane]);
    out[n * C + lane] = fmaxf(o, 0.0f);
}

// ---------------------------------------------------------------------------
// Launch. ws layout:
//   h        : float[3,200,000]  (12.8 MB)
//   deg      : int[50,000]
//   rowptr   : int[50,001]
//   cursor   : int[50,000]
//   ebuf     : int[800,000]
//   partial  : int[NBLK]
//   blockoff : int[NBLK]
// ---------------------------------------------------------------------------
extern "C" void kernel_launch(void* const* d_in, const int* in_sizes, int n_in,
                              void* d_out, int out_size, void* d_ws, size_t ws_size,
                              hipStream_t stream)
{
    const float* x    = (const float*)d_in[0];
    const int*   ei   = (const int*)d_in[1];
    // d_in[2] = edge_attr: drops out for kernel_size=1 SplineConv
    const float* W    = (const float*)d_in[3];
    const float* R    = (const float*)d_in[4];
    const float* bias = (const float*)d_in[5];

    char* wsb = (char*)d_ws;
    float* h      = (float*)wsb;
    size_t off    = (size_t)N_NODES * C * sizeof(float);
    int*   deg    = (int*)(wsb + off);  off += ((N_NODES + 3) & ~3) * sizeof(int);
    int*   rowptr = (int*)(wsb + off);  off += ((N_NODES + 4) & ~3) * sizeof(int);
    int*   cursor = (int*)(wsb + off);  off += ((N_NODES + 3) & ~3) * sizeof(int);
    int*   ebuf   = (int*)(wsb + off);  off += (size_t)N_EDGES * sizeof(int);
    int*   partial  = (int*)(wsb + off); off += ((NBLK + 3) & ~3) * sizeof(int);
    int*   blockoff = (int*)(wsb + off);
    float* out    = (float*)d_out;

    hipMemsetAsync(deg, 0, N_NODES * sizeof(int), stream);

    node_transform<<<2048, 256, 0, stream>>>(x, W, R, bias, h, out);
    count_deg     <<<2048, 256, 0, stream>>>(ei, deg);
    block_sums    <<<NBLK, 256, 0, stream>>>(deg, partial);
    scan_partials <<<1, 64, 0, stream>>>(partial, blockoff);
    write_scan    <<<NBLK, 256, 0, stream>>>(deg, blockoff, rowptr, cursor);
    build_csr     <<<2048, 256, 0, stream>>>(ei, cursor, ebuf);
    aggregate     <<<(N_NODES + 3) / 4, 256, 0, stream>>>(rowptr, ebuf, h, out);
}

// Round 4
// 145.107 us; speedup vs baseline: 5.4528x; 1.2759x over previous
//
#include <hip/hip_runtime.h>

#define N_NODES 50000
#define N_EDGES 800000
#define C 64                         // channels (C_IN == C_HID == 64)
#define TILE_NODES 64
#define NTILES ((N_NODES + TILE_NODES - 1) / TILE_NODES)   // 782
#define NB 256                       // nodes per scan block
#define NBLK ((N_NODES + NB - 1) / NB)   // 196 scan blocks
#define COUNT_BLOCKS 256

// ---------------------------------------------------------------------------
// Kernel 1 (fused): role-split by blockIdx.
//  blocks [0, NTILES): per-64-node-tile transform.
//    h = x @ W (to ws), r_out = x @ root + bias (to d_out).
//    Lane c owns output channel c. W/R columns held in REGISTERS (128 VGPR),
//    loaded once per wave via coalesced global reads (W row k is contiguous,
//    lane-stride-1). x tile staged in LDS; x[n][k] broadcast to the wave via
//    uniform-address ds_read_b128 (DS pipe, overlaps VALU). 2 nodes in
//    flight = 4 independent fma chains.
//  blocks [NTILES, NTILES+COUNT_BLOCKS): degree histogram (int atomics).
// ---------------------------------------------------------------------------
__global__ __launch_bounds__(256, 3) void transform_and_count(
    const float* __restrict__ x,
    const float* __restrict__ W,
    const float* __restrict__ R,
    const float* __restrict__ bias,
    const int*   __restrict__ ei,
    float* __restrict__ h,
    float* __restrict__ r_out,
    int*   __restrict__ deg)
{
    if ((int)blockIdx.x >= NTILES) {
        // ---- degree-count role ----
        const int t0 = (blockIdx.x - NTILES) * 256 + threadIdx.x;
        const int stride = COUNT_BLOCKS * 256;
        for (int e = t0; e < N_EDGES; e += stride)
            atomicAdd(&deg[ei[N_EDGES + e]], 1);
        return;
    }

    // ---- transform role ----
    __shared__ float xs[TILE_NODES][C];          // 16 KB

    const int lane = threadIdx.x & 63;
    const int wid  = threadIdx.x >> 6;

    // W/R columns into registers (coalesced: row k contiguous, lane-stride-1).
    float wcol[C], rcol[C];
    #pragma unroll
    for (int k = 0; k < C; ++k) {
        wcol[k] = W[k * C + lane];
        rcol[k] = R[k * C + lane];
    }
    const float b = bias[lane];

    const int tileBase = blockIdx.x * TILE_NODES;
    const int nvalid   = min(TILE_NODES, N_NODES - tileBase);  // 64 or 16 here

    // stage x tile (coalesced float4)
    {
        const float4* xsrc = (const float4*)(x + (size_t)tileBase * C);
        const int nflt4 = (nvalid * C) >> 2;
        for (int i = threadIdx.x; i < nflt4; i += 256)
            ((float4*)xs)[i] = xsrc[i];
    }
    __syncthreads();

    // each wave owns 16 consecutive nodes of the tile; nvalid is a multiple
    // of 16 for this problem size (50000 = 781*64 + 16).
    const int myBase = wid << 4;
    const int myCnt  = min(16, nvalid - myBase);   // 16 or <=0

    for (int j = 0; j + 1 < myCnt + 1 && j < 16; j += 2) {
        if (j >= myCnt) break;
        const int n0 = myBase + j;
        const int n1 = n0 + 1;                     // myCnt is even (16)
        float ah0 = 0.f, ar0 = 0.f, ah1 = 0.f, ar1 = 0.f;
        #pragma unroll
        for (int k = 0; k < C; k += 4) {
            const float4 x0 = *(const float4*)&xs[n0][k];   // uniform -> broadcast
            const float4 x1 = *(const float4*)&xs[n1][k];
            ah0 = fmaf(x0.x, wcol[k + 0], ah0);
            ah1 = fmaf(x1.x, wcol[k + 0], ah1);
            ar0 = fmaf(x0.x, rcol[k + 0], ar0);
            ar1 = fmaf(x1.x, rcol[k + 0], ar1);
            ah0 = fmaf(x0.y, wcol[k + 1], ah0);
            ah1 = fmaf(x1.y, wcol[k + 1], ah1);
            ar0 = fmaf(x0.y, rcol[k + 1], ar0);
            ar1 = fmaf(x1.y, rcol[k + 1], ar1);
            ah0 = fmaf(x0.z, wcol[k + 2], ah0);
            ah1 = fmaf(x1.z, wcol[k + 2], ah1);
            ar0 = fmaf(x0.z, rcol[k + 2], ar0);
            ar1 = fmaf(x1.z, rcol[k + 2], ar1);
            ah0 = fmaf(x0.w, wcol[k + 3], ah0);
            ah1 = fmaf(x1.w, wcol[k + 3], ah1);
            ar0 = fmaf(x0.w, rcol[k + 3], ar0);
            ar1 = fmaf(x1.w, rcol[k + 3], ar1);
        }
        float* hp = h     + (size_t)(tileBase + n0) * C + lane;
        float* rp = r_out + (size_t)(tileBase + n0) * C + lane;
        hp[0] = ah0;  hp[C] = ah1;
        rp[0] = ar0 + b;  rp[C] = ar1 + b;
    }
}

// ---------------------------------------------------------------------------
// Kernel 2a: per-block degree sums.
// ---------------------------------------------------------------------------
__global__ __launch_bounds__(256) void block_sums(
    const int* __restrict__ deg, int* __restrict__ partial)
{
    const int i = blockIdx.x * NB + threadIdx.x;
    int v = (i < N_NODES) ? deg[i] : 0;
    #pragma unroll
    for (int off = 32; off; off >>= 1) v += __shfl_down(v, off);
    __shared__ int ws4[4];
    if ((threadIdx.x & 63) == 0) ws4[threadIdx.x >> 6] = v;
    __syncthreads();
    if (threadIdx.x == 0)
        partial[blockIdx.x] = ws4[0] + ws4[1] + ws4[2] + ws4[3];
}

// ---------------------------------------------------------------------------
// Kernel 2b: exclusive scan of the 196 block partials. Single wave.
// ---------------------------------------------------------------------------
__global__ __launch_bounds__(64) void scan_partials(
    const int* __restrict__ partial, int* __restrict__ blockoff)
{
    const int lane = threadIdx.x;          // 0..63, 4 partials per lane
    const int base = lane * 4;
    int s0 = (base + 0 < NBLK) ? partial[base + 0] : 0;
    int s1 = (base + 1 < NBLK) ? partial[base + 1] : 0;
    int s2 = (base + 2 < NBLK) ? partial[base + 2] : 0;
    int s3 = (base + 3 < NBLK) ? partial[base + 3] : 0;
    const int tot = s0 + s1 + s2 + s3;
    int incl = tot;
    #pragma unroll
    for (int off = 1; off < 64; off <<= 1) {
        const int t = __shfl_up(incl, off);
        if (lane >= off) incl += t;
    }
    int run = incl - tot;                  // exclusive
    if (base + 0 < NBLK) blockoff[base + 0] = run;          run += s0;
    if (base + 1 < NBLK) blockoff[base + 1] = run;          run += s1;
    if (base + 2 < NBLK) blockoff[base + 2] = run;          run += s2;
    if (base + 3 < NBLK) blockoff[base + 3] = run;
}

// ---------------------------------------------------------------------------
// Kernel 2c: in-block exclusive scan + block offset -> rowptr, cursor.
// ---------------------------------------------------------------------------
__global__ __launch_bounds__(256) void write_scan(
    const int* __restrict__ deg, const int* __restrict__ blockoff,
    int* __restrict__ rowptr, int* __restrict__ cursor)
{
    const int i = blockIdx.x * NB + threadIdx.x;
    const int v = (i < N_NODES) ? deg[i] : 0;
    const int lane = threadIdx.x & 63;
    const int w    = threadIdx.x >> 6;
    int incl = v;
    #pragma unroll
    for (int off = 1; off < 64; off <<= 1) {
        const int t = __shfl_up(incl, off);
        if (lane >= off) incl += t;
    }
    __shared__ int wsum[4];
    if (lane == 63) wsum[w] = incl;
    __syncthreads();
    int woff = blockoff[blockIdx.x];
    for (int k = 0; k < 4; ++k) if (k < w) woff += wsum[k];
    const int excl = incl - v + woff;
    if (i < N_NODES) {
        rowptr[i] = excl;
        cursor[i] = excl;
        if (i == N_NODES - 1) rowptr[N_NODES] = excl + v;
    }
}

// ---------------------------------------------------------------------------
// Kernel 3: place each edge's src id into its destination's CSR segment.
// ---------------------------------------------------------------------------
__global__ __launch_bounds__(256) void build_csr(
    const int* __restrict__ ei, int* __restrict__ cursor, int* __restrict__ ebuf)
{
    const int stride = gridDim.x * blockDim.x;
    for (int e = blockIdx.x * blockDim.x + threadIdx.x; e < N_EDGES; e += stride) {
        const int dst = ei[N_EDGES + e];
        const int pos = atomicAdd(&cursor[dst], 1);
        ebuf[pos] = ei[e];                       // src
    }
}

// ---------------------------------------------------------------------------
// Kernel 4: gather-aggregate + finalize. One wave per node, lane c = channel c.
// out = relu( sum_{j in N(i)} h[j] / max(deg,1) + out )   (out holds x@root+b)
// ---------------------------------------------------------------------------
__global__ __launch_bounds__(256) void aggregate(
    const int* __restrict__ rowptr,
    const int* __restrict__ ebuf,
    const float* __restrict__ h,
    float* __restrict__ out)
{
    const int lane = threadIdx.x & 63;
    const int wid  = threadIdx.x >> 6;
    const int n    = blockIdx.x * 4 + wid;       // 4 waves per block
    if (n >= N_NODES) return;

    const int beg = rowptr[n];
    const int end = rowptr[n + 1];

    float acc = 0.0f;
    for (int base = beg; base < end; base += 64) {
        const int m = min(64, end - base);
        const int sid = (base + lane < end) ? ebuf[base + lane] : 0;
        int j = 0;
        for (; j + 4 <= m; j += 4) {
            const int s0 = __shfl(sid, j + 0);
            const int s1 = __shfl(sid, j + 1);
            const int s2 = __shfl(sid, j + 2);
            const int s3 = __shfl(sid, j + 3);
            const float v0 = h[s0 * C + lane];
            const float v1 = h[s1 * C + lane];
            const float v2 = h[s2 * C + lane];
            const float v3 = h[s3 * C + lane];
            acc += (v0 + v1) + (v2 + v3);
        }
        for (; j < m; ++j) {
            const int s = __shfl(sid, j);
            acc += h[s * C + lane];
        }
    }

    const float d   = (float)(end - beg);
    const float inv = 1.0f / fmaxf(d, 1.0f);
    const float o   = fmaf(acc, inv, out[n * C + lane]);
    out[n * C + lane] = fmaxf(o, 0.0f);
}

// ---------------------------------------------------------------------------
// Launch. ws layout:
//   h        : float[3,200,000]  (12.8 MB)
//   deg      : int[50,000]
//   rowptr   : int[50,001]
//   cursor   : int[50,000]
//   ebuf     : int[800,000]
//   partial  : int[NBLK]
//   blockoff : int[NBLK]
// ---------------------------------------------------------------------------
extern "C" void kernel_launch(void* const* d_in, const int* in_sizes, int n_in,
                              void* d_out, int out_size, void* d_ws, size_t ws_size,
                              hipStream_t stream)
{
    const float* x    = (const float*)d_in[0];
    const int*   ei   = (const int*)d_in[1];
    // d_in[2] = edge_attr: drops out for kernel_size=1 SplineConv
    const float* W    = (const float*)d_in[3];
    const float* R    = (const float*)d_in[4];
    const float* bias = (const float*)d_in[5];

    char* wsb = (char*)d_ws;
    float* h      = (float*)wsb;
    size_t off    = (size_t)N_NODES * C * sizeof(float);
    int*   deg    = (int*)(wsb + off);  off += ((N_NODES + 3) & ~3) * sizeof(int);
    int*   rowptr = (int*)(wsb + off);  off += ((N_NODES + 4) & ~3) * sizeof(int);
    int*   cursor = (int*)(wsb + off);  off += ((N_NODES + 3) & ~3) * sizeof(int);
    int*   ebuf   = (int*)(wsb + off);  off += (size_t)N_EDGES * sizeof(int);
    int*   partial  = (int*)(wsb + off); off += ((NBLK + 3) & ~3) * sizeof(int);
    int*   blockoff = (int*)(wsb + off);
    float* out    = (float*)d_out;

    hipMemsetAsync(deg, 0, N_NODES * sizeof(int), stream);

    transform_and_count<<<NTILES + COUNT_BLOCKS, 256, 0, stream>>>(
        x, W, R, bias, ei, h, out, deg);
    block_sums    <<<NBLK, 256, 0, stream>>>(deg, partial);
    scan_partials <<<1, 64, 0, stream>>>(partial, blockoff);
    write_scan    <<<NBLK, 256, 0, stream>>>(deg, blockoff, rowptr, cursor);
    build_csr     <<<2048, 256, 0, stream>>>(ei, cursor, ebuf);
    aggregate     <<<(N_NODES + 3) / 4, 256, 0, stream>>>(rowptr, ebuf, h, out);
}

// Round 5
// 130.230 us; speedup vs baseline: 6.0757x; 1.1142x over previous
//
#include <hip/hip_runtime.h>

#define N_NODES 50000
#define N_EDGES 800000
#define C 64                         // channels (C_IN == C_HID == 64)
#define TILE_NODES 64
#define NTILES ((N_NODES + TILE_NODES - 1) / TILE_NODES)   // 782
#define NB 256                       // nodes per scan block
#define NBLK ((N_NODES + NB - 1) / NB)   // 196 scan blocks
#define COUNT_BLOCKS 256
// edge binning
#define BUCKET_NODES 256
#define NBUCK ((N_NODES + BUCKET_NODES - 1) / BUCKET_NODES) // 196
#define BUCKET_CAP 6144              // mean 4082, +32 sigma
#define BIN_CHUNK 8192
#define NBIN_BLOCKS ((N_EDGES + BIN_CHUNK - 1) / BIN_CHUNK) // 98

// ---------------------------------------------------------------------------
// Kernel 1 (fused, role-split by blockIdx):
//  [0, NTILES)        : h = x @ W            (weights in 64 regs/lane)
//  [NTILES, 2*NTILES) : out = x @ root + bias
//  [2*NTILES, +COUNT_BLOCKS): degree histogram (int atomics)
// One 64-reg weight column per lane -> no spill. 4 nodes in flight for ILP.
// x tile staged in LDS, broadcast via uniform-address float4 reads.
// ---------------------------------------------------------------------------
__global__ __launch_bounds__(256) void transform_and_count(
    const float* __restrict__ x,
    const float* __restrict__ W,
    const float* __restrict__ R,
    const float* __restrict__ bias,
    const int*   __restrict__ ei,
    float* __restrict__ h,
    float* __restrict__ r_out,
    int*   __restrict__ deg)
{
    const int bid = blockIdx.x;
    if (bid >= 2 * NTILES) {
        // ---- degree-count role ----
        const int t0 = (bid - 2 * NTILES) * 256 + threadIdx.x;
        const int stride = COUNT_BLOCKS * 256;
        for (int e = t0; e < N_EDGES; e += stride)
            atomicAdd(&deg[ei[N_EDGES + e]], 1);
        return;
    }

    const int  kind = (bid >= NTILES);           // 0: W->h, 1: R->out
    const int  tile = kind ? bid - NTILES : bid;
    const float* M  = kind ? R : W;
    float*      dst = kind ? r_out : h;

    const int lane = threadIdx.x & 63;
    const int wid  = threadIdx.x >> 6;

    // one weight column set in registers (64 VGPR), coalesced loads
    float mc[C];
    #pragma unroll
    for (int k = 0; k < C; ++k) mc[k] = M[k * C + lane];
    const float b = kind ? bias[lane] : 0.0f;

    __shared__ float xs[TILE_NODES][C];          // 16 KB
    const int tileBase = tile * TILE_NODES;
    const int nvalid   = min(TILE_NODES, N_NODES - tileBase); // 64 or 16
    {
        const float4* xsrc = (const float4*)(x + (size_t)tileBase * C);
        const int nflt4 = (nvalid * C) >> 2;
        for (int i = threadIdx.x; i < nflt4; i += 256)
            ((float4*)xs)[i] = xsrc[i];
    }
    __syncthreads();

    const int myBase = wid << 4;                 // 16 nodes per wave
    if (myBase >= nvalid) return;
    const int myCnt = min(16, nvalid - myBase);  // 16 (50000 % 16 == 0)

    for (int j = 0; j < myCnt; j += 4) {
        const int n0 = myBase + j;
        float a0 = 0.f, a1 = 0.f, a2 = 0.f, a3 = 0.f;
        #pragma unroll
        for (int k = 0; k < C; k += 4) {
            const float4 x0 = *(const float4*)&xs[n0 + 0][k];
            const float4 x1 = *(const float4*)&xs[n0 + 1][k];
            const float4 x2 = *(const float4*)&xs[n0 + 2][k];
            const float4 x3 = *(const float4*)&xs[n0 + 3][k];
            a0 = fmaf(x0.x, mc[k + 0], a0);
            a1 = fmaf(x1.x, mc[k + 0], a1);
            a2 = fmaf(x2.x, mc[k + 0], a2);
            a3 = fmaf(x3.x, mc[k + 0], a3);
            a0 = fmaf(x0.y, mc[k + 1], a0);
            a1 = fmaf(x1.y, mc[k + 1], a1);
            a2 = fmaf(x2.y, mc[k + 1], a2);
            a3 = fmaf(x3.y, mc[k + 1], a3);
            a0 = fmaf(x0.z, mc[k + 2], a0);
            a1 = fmaf(x1.z, mc[k + 2], a1);
            a2 = fmaf(x2.z, mc[k + 2], a2);
            a3 = fmaf(x3.z, mc[k + 2], a3);
            a0 = fmaf(x0.w, mc[k + 3], a0);
            a1 = fmaf(x1.w, mc[k + 3], a1);
            a2 = fmaf(x2.w, mc[k + 3], a2);
            a3 = fmaf(x3.w, mc[k + 3], a3);
        }
        float* dp = dst + (size_t)(tileBase + n0) * C + lane;
        dp[0 * C] = a0 + b;
        dp[1 * C] = a1 + b;
        dp[2 * C] = a2 + b;
        dp[3 * C] = a3 + b;
    }
}

// ---------------------------------------------------------------------------
// Kernel 2a: per-block degree sums.
// ---------------------------------------------------------------------------
__global__ __launch_bounds__(256) void block_sums(
    const int* __restrict__ deg, int* __restrict__ partial)
{
    const int i = blockIdx.x * NB + threadIdx.x;
    int v = (i < N_NODES) ? deg[i] : 0;
    #pragma unroll
    for (int off = 32; off; off >>= 1) v += __shfl_down(v, off);
    __shared__ int ws4[4];
    if ((threadIdx.x & 63) == 0) ws4[threadIdx.x >> 6] = v;
    __syncthreads();
    if (threadIdx.x == 0)
        partial[blockIdx.x] = ws4[0] + ws4[1] + ws4[2] + ws4[3];
}

// ---------------------------------------------------------------------------
// Kernel 2b: exclusive scan of the 196 block partials. Single wave.
// ---------------------------------------------------------------------------
__global__ __launch_bounds__(64) void scan_partials(
    const int* __restrict__ partial, int* __restrict__ blockoff)
{
    const int lane = threadIdx.x;          // 0..63, 4 partials per lane
    const int base = lane * 4;
    int s0 = (base + 0 < NBLK) ? partial[base + 0] : 0;
    int s1 = (base + 1 < NBLK) ? partial[base + 1] : 0;
    int s2 = (base + 2 < NBLK) ? partial[base + 2] : 0;
    int s3 = (base + 3 < NBLK) ? partial[base + 3] : 0;
    const int tot = s0 + s1 + s2 + s3;
    int incl = tot;
    #pragma unroll
    for (int off = 1; off < 64; off <<= 1) {
        const int t = __shfl_up(incl, off);
        if (lane >= off) incl += t;
    }
    int run = incl - tot;                  // exclusive
    if (base + 0 < NBLK) blockoff[base + 0] = run;          run += s0;
    if (base + 1 < NBLK) blockoff[base + 1] = run;          run += s1;
    if (base + 2 < NBLK) blockoff[base + 2] = run;          run += s2;
    if (base + 3 < NBLK) blockoff[base + 3] = run;
}

// ---------------------------------------------------------------------------
// Kernel 2c: in-block exclusive scan + block offset -> rowptr.
// ---------------------------------------------------------------------------
__global__ __launch_bounds__(256) void write_scan(
    const int* __restrict__ deg, const int* __restrict__ blockoff,
    int* __restrict__ rowptr)
{
    const int i = blockIdx.x * NB + threadIdx.x;
    const int v = (i < N_NODES) ? deg[i] : 0;
    const int lane = threadIdx.x & 63;
    const int w    = threadIdx.x >> 6;
    int incl = v;
    #pragma unroll
    for (int off = 1; off < 64; off <<= 1) {
        const int t = __shfl_up(incl, off);
        if (lane >= off) incl += t;
    }
    __shared__ int wsum[4];
    if (lane == 63) wsum[w] = incl;
    __syncthreads();
    int woff = blockoff[blockIdx.x];
    for (int k = 0; k < 4; ++k) if (k < w) woff += wsum[k];
    const int excl = incl - v + woff;
    if (i < N_NODES) {
        rowptr[i] = excl;
        if (i == N_NODES - 1) rowptr[N_NODES] = excl + v;
    }
}

// ---------------------------------------------------------------------------
// Kernel 3a: bin edges by dst>>8 into per-bucket append regions.
// Entry packed as (src<<8)|(dst&255): src < 50000 < 2^16, so it fits 24 bits.
// Block-local LDS counts -> one bulk global atomic per (block,bucket) ->
// semi-contiguous packed writes (write-amp ~1 vs 16x of naive scatter).
// ---------------------------------------------------------------------------
__global__ __launch_bounds__(256) void bin_edges(
    const int* __restrict__ ei,
    int* __restrict__ bucketCursor,
    int* __restrict__ bucketbuf)
{
    __shared__ int cnt[NBUCK], cnt2[NBUCK], gb[NBUCK];
    for (int i = threadIdx.x; i < NBUCK; i += 256) { cnt[i] = 0; cnt2[i] = 0; }
    __syncthreads();

    const int e0 = blockIdx.x * BIN_CHUNK;
    const int e1 = min(e0 + BIN_CHUNK, N_EDGES);

    for (int e = e0 + threadIdx.x; e < e1; e += 256)
        atomicAdd(&cnt[((unsigned)ei[N_EDGES + e]) >> 8], 1);
    __syncthreads();

    for (int i = threadIdx.x; i < NBUCK; i += 256)
        gb[i] = atomicAdd(&bucketCursor[i], cnt[i]);
    __syncthreads();

    for (int e = e0 + threadIdx.x; e < e1; e += 256) {
        const int src = ei[e];
        const int dst = ei[N_EDGES + e];
        const int bkt = ((unsigned)dst) >> 8;
        const int off = gb[bkt] + atomicAdd(&cnt2[bkt], 1);
        bucketbuf[bkt * BUCKET_CAP + off] = (src << 8) | (dst & 255);
    }
}

// ---------------------------------------------------------------------------
// Kernel 3b: per-bucket CSR placement. One block per bucket; LDS cursors;
// writes land in the bucket's CONTIGUOUS ebuf window [rowptr[lo], rowptr[hi]).
// ---------------------------------------------------------------------------
__global__ __launch_bounds__(256) void csr_place(
    const int* __restrict__ bucketCursor,
    const int* __restrict__ bucketbuf,
    const int* __restrict__ rowptr,
    int* __restrict__ ebuf)
{
    __shared__ int lcur[BUCKET_NODES];
    const int b  = blockIdx.x;
    const int lo = b * BUCKET_NODES;
    const int nn = min(BUCKET_NODES, N_NODES - lo);
    for (int i = threadIdx.x; i < nn; i += 256) lcur[i] = rowptr[lo + i];
    __syncthreads();

    const int cnt = bucketCursor[b];
    const int* buf = bucketbuf + b * BUCKET_CAP;
    for (int k = threadIdx.x; k < cnt; k += 256) {
        const int p   = buf[k];
        const int pos = atomicAdd(&lcur[p & 255], 1);
        ebuf[pos] = p >> 8;
    }
}

// ---------------------------------------------------------------------------
// Kernel 4: gather-aggregate + finalize. One wave per node, lane c = channel c.
// out = relu( sum_{j in N(i)} h[j] / max(deg,1) + out )   (out holds x@root+b)
// ---------------------------------------------------------------------------
__global__ __launch_bounds__(256) void aggregate(
    const int* __restrict__ rowptr,
    const int* __restrict__ ebuf,
    const float* __restrict__ h,
    float* __restrict__ out)
{
    const int lane = threadIdx.x & 63;
    const int wid  = threadIdx.x >> 6;
    const int n    = blockIdx.x * 4 + wid;       // 4 waves per block
    if (n >= N_NODES) return;

    const int beg = rowptr[n];
    const int end = rowptr[n + 1];

    float acc = 0.0f;
    for (int base = beg; base < end; base += 64) {
        const int m = min(64, end - base);
        const int sid = (base + lane < end) ? ebuf[base + lane] : 0;
        int j = 0;
        for (; j + 4 <= m; j += 4) {
            const int s0 = __shfl(sid, j + 0);
            const int s1 = __shfl(sid, j + 1);
            const int s2 = __shfl(sid, j + 2);
            const int s3 = __shfl(sid, j + 3);
            const float v0 = h[s0 * C + lane];
            const float v1 = h[s1 * C + lane];
            const float v2 = h[s2 * C + lane];
            const float v3 = h[s3 * C + lane];
            acc += (v0 + v1) + (v2 + v3);
        }
        for (; j < m; ++j) {
            const int s = __shfl(sid, j);
            acc += h[s * C + lane];
        }
    }

    const float d   = (float)(end - beg);
    const float inv = 1.0f / fmaxf(d, 1.0f);
    const float o   = fmaf(acc, inv, out[n * C + lane]);
    out[n * C + lane] = fmaxf(o, 0.0f);
}

// ---------------------------------------------------------------------------
// Launch. ws layout:
//   h            : float[3,200,000]        (12.8 MB)
//   deg          : int[50,000]     \  one contiguous memset
//   bucketCursor : int[256]        /
//   rowptr       : int[50,004]
//   partial      : int[200]
//   blockoff     : int[200]
//   ebuf         : int[800,000]            (3.2 MB)
//   bucketbuf    : int[196*6144]           (4.8 MB)
//   total ~21.3 MB
// ---------------------------------------------------------------------------
extern "C" void kernel_launch(void* const* d_in, const int* in_sizes, int n_in,
                              void* d_out, int out_size, void* d_ws, size_t ws_size,
                              hipStream_t stream)
{
    const float* x    = (const float*)d_in[0];
    const int*   ei   = (const int*)d_in[1];
    // d_in[2] = edge_attr: drops out for kernel_size=1 SplineConv
    const float* W    = (const float*)d_in[3];
    const float* R    = (const float*)d_in[4];
    const float* bias = (const float*)d_in[5];

    char* wsb = (char*)d_ws;
    float* h          = (float*)wsb;
    size_t off        = (size_t)N_NODES * C * sizeof(float);
    int*   deg        = (int*)(wsb + off);  off += N_NODES * sizeof(int);
    int*   bucketCursor = (int*)(wsb + off); off += 256 * sizeof(int);
    int*   rowptr     = (int*)(wsb + off);  off += ((N_NODES + 4) & ~3) * sizeof(int);
    int*   partial    = (int*)(wsb + off);  off += 200 * sizeof(int);
    int*   blockoff   = (int*)(wsb + off);  off += 200 * sizeof(int);
    int*   ebuf       = (int*)(wsb + off);  off += (size_t)N_EDGES * sizeof(int);
    int*   bucketbuf  = (int*)(wsb + off);
    float* out        = (float*)d_out;

    // zero deg + bucketCursor in one shot (adjacent)
    hipMemsetAsync(deg, 0, (N_NODES + 256) * sizeof(int), stream);

    transform_and_count<<<2 * NTILES + COUNT_BLOCKS, 256, 0, stream>>>(
        x, W, R, bias, ei, h, out, deg);
    block_sums    <<<NBLK, 256, 0, stream>>>(deg, partial);
    scan_partials <<<1, 64, 0, stream>>>(partial, blockoff);
    write_scan    <<<NBLK, 256, 0, stream>>>(deg, blockoff, rowptr);
    bin_edges     <<<NBIN_BLOCKS, 256, 0, stream>>>(ei, bucketCursor, bucketbuf);
    csr_place     <<<NBUCK, 256, 0, stream>>>(bucketCursor, bucketbuf, rowptr, ebuf);
    aggregate     <<<(N_NODES + 3) / 4, 256, 0, stream>>>(rowptr, ebuf, h, out);
}

// Round 6
// 87.095 us; speedup vs baseline: 9.0847x; 1.4953x over previous
//
#include <hip/hip_runtime.h>

#define N_NODES 50000
#define N_EDGES 800000
#define C 64                          // channels (C_IN == C_HID == 64)
// edge binning
#define BUCKET_NODES 256
#define NBUCK ((N_NODES + BUCKET_NODES - 1) / BUCKET_NODES)  // 196
#define BUCKET_CAP 6144               // mean 4096, +32 sigma (proven on this graph)
#define BIN_CHUNK 8192
#define NBIN_BLOCKS ((N_EDGES + BIN_CHUNK - 1) / BIN_CHUNK)  // 98
// mfma epilogue
#define NMFMA ((N_NODES + 63) / 64)   // 782

typedef __attribute__((ext_vector_type(8))) short bf16x8;
typedef __attribute__((ext_vector_type(4))) float f32x4;

__device__ inline unsigned short f2bf(float f) {          // round-to-nearest-even
    union { float f; unsigned u; } v; v.f = f;
    unsigned r = v.u + 0x7FFF + ((v.u >> 16) & 1);
    return (unsigned short)(r >> 16);
}
__device__ inline float bf2f(unsigned short h) {
    union { unsigned u; float f; } v; v.u = (unsigned)h << 16;
    return v.f;
}

// ---------------------------------------------------------------------------
// Kernel 1: prep. Block 0 repacks W,root into bf16 MFMA B-fragments;
// blocks 1.. convert x to bf16 (row-major, same layout).
// B-frag layout for mfma_f32_16x16x32_bf16: lane l holds
//   B[k = ks*32 + (l>>4)*8 + j][col = ct*16 + (l&15)], j=0..7.
// wpack slot s = f*64 + lane, f = mat*8 + ks*4 + ct  (mat 0=W, 1=root).
// ---------------------------------------------------------------------------
__global__ __launch_bounds__(256) void prep(
    const float* __restrict__ x,
    const float* __restrict__ W,
    const float* __restrict__ R,
    unsigned short* __restrict__ xbf,
    uint4* __restrict__ wpack)
{
    if (blockIdx.x == 0) {
        for (int s = threadIdx.x; s < 1024; s += 256) {
            const int f    = s >> 6;
            const int lane = s & 63;
            const int mat  = f >> 3, ks = (f >> 2) & 1, ct = f & 3;
            const float* src = mat ? R : W;
            const int kbase = ks * 32 + (lane >> 4) * 8;
            const int col   = ct * 16 + (lane & 15);
            unsigned wd[4];
            #pragma unroll
            for (int jj = 0; jj < 4; ++jj) {
                const unsigned lo16 = f2bf(src[(kbase + 2*jj    ) * C + col]);
                const unsigned hi16 = f2bf(src[(kbase + 2*jj + 1) * C + col]);
                wd[jj] = lo16 | (hi16 << 16);
            }
            uint4 o; o.x = wd[0]; o.y = wd[1]; o.z = wd[2]; o.w = wd[3];
            wpack[s] = o;
        }
        return;
    }
    const int nthreads = ((int)gridDim.x - 1) * 256;
    const int total4 = (N_NODES * C) / 4;                 // 800000 float4
    for (int i = ((int)blockIdx.x - 1) * 256 + threadIdx.x; i < total4; i += nthreads) {
        const float4 v = ((const float4*)x)[i];
        ushort4 o;
        o.x = f2bf(v.x); o.y = f2bf(v.y); o.z = f2bf(v.z); o.w = f2bf(v.w);
        ((ushort4*)xbf)[i] = o;
    }
}

// ---------------------------------------------------------------------------
// Kernel 2: bin edges by dst>>8. Entry = (src<<8)|(dst&255).
// Block-local LDS counts -> one bulk atomic per (block,bucket) -> packed
// appends. bucketCursor ends up holding the per-bucket totals.
// ---------------------------------------------------------------------------
__global__ __launch_bounds__(256) void bin_edges(
    const int* __restrict__ ei,
    int* __restrict__ bucketCursor,
    int* __restrict__ bucketbuf)
{
    __shared__ int cnt[NBUCK], cnt2[NBUCK], gb[NBUCK];
    for (int i = threadIdx.x; i < NBUCK; i += 256) { cnt[i] = 0; cnt2[i] = 0; }
    __syncthreads();

    const int e0 = blockIdx.x * BIN_CHUNK;
    const int e1 = min(e0 + BIN_CHUNK, N_EDGES);

    for (int e = e0 + threadIdx.x; e < e1; e += 256)
        atomicAdd(&cnt[((unsigned)ei[N_EDGES + e]) >> 8], 1);
    __syncthreads();

    for (int i = threadIdx.x; i < NBUCK; i += 256)
        gb[i] = atomicAdd(&bucketCursor[i], cnt[i]);
    __syncthreads();

    for (int e = e0 + threadIdx.x; e < e1; e += 256) {
        const int src = ei[e];
        const int dst = ei[N_EDGES + e];
        const int bkt = ((unsigned)dst) >> 8;
        const int off = gb[bkt] + atomicAdd(&cnt2[bkt], 1);
        bucketbuf[bkt * BUCKET_CAP + off] = (src << 8) | (dst & 255);
    }
}

// ---------------------------------------------------------------------------
// Kernel 3: per-bucket {stage entries, LDS degree-hist, block scan, rowptr
// write, CSR placement} — all fused. Bucket offset derived in-block by
// wave 0 scanning bucketCursor (196 ints, L2-hot).
// ---------------------------------------------------------------------------
__global__ __launch_bounds__(256) void csr_place_scan(
    const int* __restrict__ bucketCursor,
    const int* __restrict__ bucketbuf,
    int* __restrict__ rowptr,
    int* __restrict__ ebuf)
{
    __shared__ int entries[BUCKET_CAP];                   // 24 KB
    __shared__ int lcur[BUCKET_NODES];
    __shared__ int wsum[4];
    __shared__ int boffS;

    const int b    = blockIdx.x;
    const int tid  = threadIdx.x;
    const int lane = tid & 63, w = tid >> 6;
    const int lo   = b * BUCKET_NODES;
    const int nn   = min(BUCKET_NODES, N_NODES - lo);
    const int cnt  = bucketCursor[b];

    if (w == 0) {                                         // bucket-offset scan
        const int base = lane * 4;
        int s0 = (base+0 < NBUCK) ? bucketCursor[base+0] : 0;
        int s1 = (base+1 < NBUCK) ? bucketCursor[base+1] : 0;
        int s2 = (base+2 < NBUCK) ? bucketCursor[base+2] : 0;
        int s3 = (base+3 < NBUCK) ? bucketCursor[base+3] : 0;
        const int tot = s0 + s1 + s2 + s3;
        int incl = tot;
        #pragma unroll
        for (int off = 1; off < 64; off <<= 1) {
            const int t = __shfl_up(incl, off);
            if (lane >= off) incl += t;
        }
        if (lane == (b >> 2)) {
            int v = incl - tot;
            if ((b & 3) > 0) v += s0;
            if ((b & 3) > 1) v += s1;
            if ((b & 3) > 2) v += s2;
            boffS = v;
        }
    }

    lcur[tid] = 0;
    for (int k = tid; k < cnt; k += 256) entries[k] = bucketbuf[b * BUCKET_CAP + k];
    __syncthreads();

    for (int k = tid; k < cnt; k += 256)
        atomicAdd(&lcur[entries[k] & 255], 1);            // LDS degree hist
    __syncthreads();

    const int v = (tid < nn) ? lcur[tid] : 0;
    int incl = v;                                         // block exclusive scan
    #pragma unroll
    for (int off = 1; off < 64; off <<= 1) {
        const int t = __shfl_up(incl, off);
        if (lane >= off) incl += t;
    }
    if (lane == 63) wsum[w] = incl;
    __syncthreads();
    int woff = boffS;
    for (int k = 0; k < 4; ++k) if (k < w) woff += wsum[k];
    const int excl = woff + incl - v;
    __syncthreads();                                      // all v-reads done
    if (tid < nn) {
        rowptr[lo + tid] = excl;
        lcur[tid] = excl;
        if (lo + tid == N_NODES - 1) rowptr[N_NODES] = excl + v;
    }
    __syncthreads();

    for (int k = tid; k < cnt; k += 256) {                // placement
        const int p   = entries[k];
        const int pos = atomicAdd(&lcur[p & 255], 1);
        ebuf[pos] = p >> 8;
    }
}

// ---------------------------------------------------------------------------
// Kernel 4: aggregate x over incoming edges (mean), bf16 in / bf16 out.
// One wave per node, lane c = channel c.
// ---------------------------------------------------------------------------
__global__ __launch_bounds__(256) void aggregate_x(
    const int* __restrict__ rowptr,
    const int* __restrict__ ebuf,
    const unsigned short* __restrict__ xbf,
    unsigned short* __restrict__ aggxbf)
{
    const int lane = threadIdx.x & 63;
    const int wid  = threadIdx.x >> 6;
    const int n    = blockIdx.x * 4 + wid;
    if (n >= N_NODES) return;

    const int beg = rowptr[n];
    const int end = rowptr[n + 1];

    float acc = 0.0f;
    for (int base = beg; base < end; base += 64) {
        const int m = min(64, end - base);
        const int sid = (base + lane < end) ? ebuf[base + lane] : 0;
        int j = 0;
        for (; j + 4 <= m; j += 4) {
            const int s0 = __shfl(sid, j + 0);
            const int s1 = __shfl(sid, j + 1);
            const int s2 = __shfl(sid, j + 2);
            const int s3 = __shfl(sid, j + 3);
            const float v0 = bf2f(xbf[(size_t)s0 * C + lane]);
            const float v1 = bf2f(xbf[(size_t)s1 * C + lane]);
            const float v2 = bf2f(xbf[(size_t)s2 * C + lane]);
            const float v3 = bf2f(xbf[(size_t)s3 * C + lane]);
            acc += (v0 + v1) + (v2 + v3);
        }
        for (; j < m; ++j)
            acc += bf2f(xbf[(size_t)__shfl(sid, j) * C + lane]);
    }
    const float inv = 1.0f / fmaxf((float)(end - beg), 1.0f);
    aggxbf[(size_t)n * C + lane] = f2bf(acc * inv);
}

// ---------------------------------------------------------------------------
// Kernel 5: fused epilogue GEMM via MFMA:
//   out = relu( aggx @ W + x @ root + bias )
// Block = 64 nodes, 4 waves; wave w owns channels [16w,16w+16).
// A-frag: lane l holds Arow[l&15], k = (l>>4)*8+j (same k-map as B pack).
// D: col = lane&15 (channel), row = (lane>>4)*4 + reg (node) [m89-verified].
// ---------------------------------------------------------------------------
__global__ __launch_bounds__(256) void mfma_out_k(
    const unsigned short* __restrict__ xbf,
    const unsigned short* __restrict__ aggxbf,
    const uint4*  __restrict__ wpack,
    const float*  __restrict__ bias,
    float* __restrict__ out)
{
    const int tile = blockIdx.x;
    const int lane = threadIdx.x & 63;
    const int w    = threadIdx.x >> 6;        // channel tile 0..3
    const int r    = lane & 15;
    const int q    = lane >> 4;

    const bf16x8 bw0 = *(const bf16x8*)&wpack[(0*8 + 0*4 + w) * 64 + lane];
    const bf16x8 bw1 = *(const bf16x8*)&wpack[(0*8 + 1*4 + w) * 64 + lane];
    const bf16x8 br0 = *(const bf16x8*)&wpack[(1*8 + 0*4 + w) * 64 + lane];
    const bf16x8 br1 = *(const bf16x8*)&wpack[(1*8 + 1*4 + w) * 64 + lane];
    const float  bb  = bias[w * 16 + r];

    #pragma unroll
    for (int g = 0; g < 4; ++g) {
        const int nbase = tile * 64 + g * 16;
        if (nbase >= N_NODES) break;
        const unsigned short* rag = aggxbf + (size_t)(nbase + r) * C;
        const unsigned short* rx  = xbf    + (size_t)(nbase + r) * C;
        const bf16x8 a0 = *(const bf16x8*)(rag + q * 8);
        const bf16x8 a1 = *(const bf16x8*)(rag + 32 + q * 8);
        const bf16x8 a2 = *(const bf16x8*)(rx  + q * 8);
        const bf16x8 a3 = *(const bf16x8*)(rx  + 32 + q * 8);
        f32x4 acc = {0.f, 0.f, 0.f, 0.f};
        acc = __builtin_amdgcn_mfma_f32_16x16x32_bf16(a0, bw0, acc, 0, 0, 0);
        acc = __builtin_amdgcn_mfma_f32_16x16x32_bf16(a1, bw1, acc, 0, 0, 0);
        acc = __builtin_amdgcn_mfma_f32_16x16x32_bf16(a2, br0, acc, 0, 0, 0);
        acc = __builtin_amdgcn_mfma_f32_16x16x32_bf16(a3, br1, acc, 0, 0, 0);
        #pragma unroll
        for (int i = 0; i < 4; ++i) {
            const int node = nbase + q * 4 + i;
            out[(size_t)node * C + w * 16 + r] = fmaxf(acc[i] + bb, 0.f);
        }
    }
}

// ---------------------------------------------------------------------------
// Launch. ws layout (16B-aligned):
//   xbf          : ushort[3,200,000]   6.4 MB
//   aggxbf       : ushort[3,200,000]   6.4 MB
//   wpack        : uint4[1024]         16 KB
//   bucketCursor : int[256]            (memset)
//   rowptr       : int[50,008]
//   ebuf         : int[800,000]        3.2 MB
//   bucketbuf    : int[196*6144]       4.8 MB     total ~21 MB
// ---------------------------------------------------------------------------
extern "C" void kernel_launch(void* const* d_in, const int* in_sizes, int n_in,
                              void* d_out, int out_size, void* d_ws, size_t ws_size,
                              hipStream_t stream)
{
    const float* x    = (const float*)d_in[0];
    const int*   ei   = (const int*)d_in[1];
    // d_in[2] = edge_attr: drops out for kernel_size=1 SplineConv
    const float* W    = (const float*)d_in[3];
    const float* R    = (const float*)d_in[4];
    const float* bias = (const float*)d_in[5];

    char* wsb = (char*)d_ws;
    unsigned short* xbf    = (unsigned short*)wsb;
    size_t off = (size_t)N_NODES * C * sizeof(unsigned short);
    unsigned short* aggxbf = (unsigned short*)(wsb + off);
    off += (size_t)N_NODES * C * sizeof(unsigned short);
    uint4* wpack           = (uint4*)(wsb + off);  off += 1024 * sizeof(uint4);
    int*   bucketCursor    = (int*)(wsb + off);    off += 256 * sizeof(int);
    int*   rowptr          = (int*)(wsb + off);    off += ((N_NODES + 8) & ~3) * sizeof(int);
    int*   ebuf            = (int*)(wsb + off);    off += (size_t)N_EDGES * sizeof(int);
    int*   bucketbuf       = (int*)(wsb + off);
    float* out             = (float*)d_out;

    hipMemsetAsync(bucketCursor, 0, 256 * sizeof(int), stream);

    prep          <<<200, 256, 0, stream>>>(x, W, R, xbf, wpack);
    bin_edges     <<<NBIN_BLOCKS, 256, 0, stream>>>(ei, bucketCursor, bucketbuf);
    csr_place_scan<<<NBUCK, 256, 0, stream>>>(bucketCursor, bucketbuf, rowptr, ebuf);
    aggregate_x   <<<(N_NODES + 3) / 4, 256, 0, stream>>>(rowptr, ebuf, xbf, aggxbf);
    mfma_out_k    <<<NMFMA, 256, 0, stream>>>(xbf, aggxbf, wpack, bias, out);
}

// Round 7
// 72.842 us; speedup vs baseline: 10.8623x; 1.1957x over previous
//
#include <hip/hip_runtime.h>

#define N_NODES 50000
#define N_EDGES 800000
#define C 64                          // channels (C_IN == C_HID == 64)
// edge binning
#define BUCKET_NODES 256
#define NBUCK ((N_NODES + BUCKET_NODES - 1) / BUCKET_NODES)  // 196
#define BUCKET_CAP 6144               // mean 4096, +32 sigma (proven on this graph)
#define BIN_CHUNK 8192
#define NBIN_BLOCKS ((N_EDGES + BIN_CHUNK - 1) / BIN_CHUNK)  // 98
#define PREP_XBLOCKS 199
#define PB_BLOCKS (1 + PREP_XBLOCKS + NBIN_BLOCKS)           // 298
// fused aggregate+mfma
#define AGG_NODES 16
#define NAGG (N_NODES / AGG_NODES)    // 3125 exactly (no tail)
#define LDSTR 72                      // LDS row stride in shorts (144 B: 2-way bank alias max)

typedef __attribute__((ext_vector_type(8))) short bf16x8;
typedef __attribute__((ext_vector_type(4))) float f32x4;

__device__ inline unsigned short f2bf(float f) {          // round-to-nearest-even
    union { float f; unsigned u; } v; v.f = f;
    unsigned r = v.u + 0x7FFF + ((v.u >> 16) & 1);
    return (unsigned short)(r >> 16);
}
__device__ inline float bf2f(unsigned short h) {
    union { unsigned u; float f; } v; v.u = (unsigned)h << 16;
    return v.f;
}

// ---------------------------------------------------------------------------
// Kernel 0: zero the 256-int bucket cursor (replaces hipMemsetAsync dispatch).
// ---------------------------------------------------------------------------
__global__ __launch_bounds__(256) void zero_cursor(int* __restrict__ c)
{
    c[threadIdx.x] = 0;
}

// ---------------------------------------------------------------------------
// Kernel 1 (fused, role-split by blockIdx):
//   block 0            : pack W,root into bf16 MFMA B-fragments
//   blocks 1..199      : convert x -> bf16 row-major
//   blocks 200..297    : bin edges by dst>>8 (entry = (src<<8)|(dst&255))
// B-frag layout for mfma_f32_16x16x32_bf16: lane l holds
//   B[k = ks*32 + (l>>4)*8 + j][col = ct*16 + (l&15)], j=0..7.
// wpack slot s = f*64 + lane, f = mat*8 + ks*4 + ct  (mat 0=W, 1=root).
// ---------------------------------------------------------------------------
__global__ __launch_bounds__(256) void prep_bin(
    const float* __restrict__ x,
    const float* __restrict__ W,
    const float* __restrict__ R,
    const int*   __restrict__ ei,
    unsigned short* __restrict__ xbf,
    uint4* __restrict__ wpack,
    int* __restrict__ bucketCursor,
    int* __restrict__ bucketbuf)
{
    const int bid = blockIdx.x;

    if (bid == 0) {
        // ---- weight-pack role ----
        for (int s = threadIdx.x; s < 1024; s += 256) {
            const int f    = s >> 6;
            const int lane = s & 63;
            const int mat  = f >> 3, ks = (f >> 2) & 1, ct = f & 3;
            const float* src = mat ? R : W;
            const int kbase = ks * 32 + (lane >> 4) * 8;
            const int col   = ct * 16 + (lane & 15);
            unsigned wd[4];
            #pragma unroll
            for (int jj = 0; jj < 4; ++jj) {
                const unsigned lo16 = f2bf(src[(kbase + 2*jj    ) * C + col]);
                const unsigned hi16 = f2bf(src[(kbase + 2*jj + 1) * C + col]);
                wd[jj] = lo16 | (hi16 << 16);
            }
            uint4 o; o.x = wd[0]; o.y = wd[1]; o.z = wd[2]; o.w = wd[3];
            wpack[s] = o;
        }
        return;
    }

    if (bid <= PREP_XBLOCKS) {
        // ---- x-convert role ----
        const int nthreads = PREP_XBLOCKS * 256;
        const int total4 = (N_NODES * C) / 4;             // 800000 float4
        for (int i = (bid - 1) * 256 + threadIdx.x; i < total4; i += nthreads) {
            const float4 v = ((const float4*)x)[i];
            ushort4 o;
            o.x = f2bf(v.x); o.y = f2bf(v.y); o.z = f2bf(v.z); o.w = f2bf(v.w);
            ((ushort4*)xbf)[i] = o;
        }
        return;
    }

    // ---- edge-bin role ----
    __shared__ int cnt[NBUCK], cnt2[NBUCK], gb[NBUCK];
    for (int i = threadIdx.x; i < NBUCK; i += 256) { cnt[i] = 0; cnt2[i] = 0; }
    __syncthreads();

    const int bb = bid - 1 - PREP_XBLOCKS;
    const int e0 = bb * BIN_CHUNK;
    const int e1 = min(e0 + BIN_CHUNK, N_EDGES);

    for (int e = e0 + threadIdx.x; e < e1; e += 256)
        atomicAdd(&cnt[((unsigned)ei[N_EDGES + e]) >> 8], 1);
    __syncthreads();

    for (int i = threadIdx.x; i < NBUCK; i += 256)
        gb[i] = atomicAdd(&bucketCursor[i], cnt[i]);
    __syncthreads();

    for (int e = e0 + threadIdx.x; e < e1; e += 256) {
        const int src = ei[e];
        const int dst = ei[N_EDGES + e];
        const int bkt = ((unsigned)dst) >> 8;
        const int off = gb[bkt] + atomicAdd(&cnt2[bkt], 1);
        bucketbuf[bkt * BUCKET_CAP + off] = (src << 8) | (dst & 255);
    }
}

// ---------------------------------------------------------------------------
// Kernel 2: per-bucket {stage entries, LDS degree-hist, block scan, rowptr
// write, CSR placement} — all fused. Bucket offset derived in-block by
// wave 0 scanning bucketCursor (196 ints, L2-hot).
// ---------------------------------------------------------------------------
__global__ __launch_bounds__(256) void csr_place_scan(
    const int* __restrict__ bucketCursor,
    const int* __restrict__ bucketbuf,
    int* __restrict__ rowptr,
    int* __restrict__ ebuf)
{
    __shared__ int entries[BUCKET_CAP];                   // 24 KB
    __shared__ int lcur[BUCKET_NODES];
    __shared__ int wsum[4];
    __shared__ int boffS;

    const int b    = blockIdx.x;
    const int tid  = threadIdx.x;
    const int lane = tid & 63, w = tid >> 6;
    const int lo   = b * BUCKET_NODES;
    const int nn   = min(BUCKET_NODES, N_NODES - lo);
    const int cnt  = bucketCursor[b];

    if (w == 0) {                                         // bucket-offset scan
        const int base = lane * 4;
        int s0 = (base+0 < NBUCK) ? bucketCursor[base+0] : 0;
        int s1 = (base+1 < NBUCK) ? bucketCursor[base+1] : 0;
        int s2 = (base+2 < NBUCK) ? bucketCursor[base+2] : 0;
        int s3 = (base+3 < NBUCK) ? bucketCursor[base+3] : 0;
        const int tot = s0 + s1 + s2 + s3;
        int incl = tot;
        #pragma unroll
        for (int off = 1; off < 64; off <<= 1) {
            const int t = __shfl_up(incl, off);
            if (lane >= off) incl += t;
        }
        if (lane == (b >> 2)) {
            int v = incl - tot;
            if ((b & 3) > 0) v += s0;
            if ((b & 3) > 1) v += s1;
            if ((b & 3) > 2) v += s2;
            boffS = v;
        }
    }

    lcur[tid] = 0;
    for (int k = tid; k < cnt; k += 256) entries[k] = bucketbuf[b * BUCKET_CAP + k];
    __syncthreads();

    for (int k = tid; k < cnt; k += 256)
        atomicAdd(&lcur[entries[k] & 255], 1);            // LDS degree hist
    __syncthreads();

    const int v = (tid < nn) ? lcur[tid] : 0;
    int incl = v;                                         // block exclusive scan
    #pragma unroll
    for (int off = 1; off < 64; off <<= 1) {
        const int t = __shfl_up(incl, off);
        if (lane >= off) incl += t;
    }
    if (lane == 63) wsum[w] = incl;
    __syncthreads();
    int woff = boffS;
    for (int k = 0; k < 4; ++k) if (k < w) woff += wsum[k];
    const int excl = woff + incl - v;
    __syncthreads();                                      // all v-reads done
    if (tid < nn) {
        rowptr[lo + tid] = excl;
        lcur[tid] = excl;
        if (lo + tid == N_NODES - 1) rowptr[N_NODES] = excl + v;
    }
    __syncthreads();

    for (int k = tid; k < cnt; k += 256) {                // placement
        const int p   = entries[k];
        const int pos = atomicAdd(&lcur[p & 255], 1);
        ebuf[pos] = p >> 8;
    }
}

// ---------------------------------------------------------------------------
// Kernel 3 (fused): aggregate x (mean over incoming edges) into an LDS tile,
// then epilogue GEMM via MFMA:  out = relu( aggx @ W + x @ root + bias ).
// Block = 16 nodes (50000 = 3125*16, no tail), 4 waves.
//  Phase 1: wave w aggregates nodes w*4..w*4+3 (lane c = channel c) -> LDS bf16.
//  Phase 2: wave w owns channel tile w; A-frags: aggx from LDS (row stride 72
//           shorts -> ds_read_b128 lands 2-way bank alias = free), x from
//           global. D layout: col=lane&15 (channel), row=(lane>>4)*4+reg (node).
// ---------------------------------------------------------------------------
__global__ __launch_bounds__(256) void agg_mfma(
    const int* __restrict__ rowptr,
    const int* __restrict__ ebuf,
    const unsigned short* __restrict__ xbf,
    const uint4*  __restrict__ wpack,
    const float*  __restrict__ bias,
    float* __restrict__ out)
{
    __shared__ unsigned short aggs[AGG_NODES][LDSTR];

    const int lane = threadIdx.x & 63;
    const int w    = threadIdx.x >> 6;
    const int tileBase = (int)blockIdx.x * AGG_NODES;

    // ---- phase 1: aggregation (4 nodes per wave) ----
    #pragma unroll
    for (int i = 0; i < 4; ++i) {
        const int n   = tileBase + w * 4 + i;
        const int beg = rowptr[n];
        const int end = rowptr[n + 1];
        float acc = 0.0f;
        for (int base = beg; base < end; base += 64) {
            const int m = min(64, end - base);
            const int sid = (base + lane < end) ? ebuf[base + lane] : 0;
            int j = 0;
            for (; j + 4 <= m; j += 4) {
                const int s0 = __shfl(sid, j + 0);
                const int s1 = __shfl(sid, j + 1);
                const int s2 = __shfl(sid, j + 2);
                const int s3 = __shfl(sid, j + 3);
                const float v0 = bf2f(xbf[(size_t)s0 * C + lane]);
                const float v1 = bf2f(xbf[(size_t)s1 * C + lane]);
                const float v2 = bf2f(xbf[(size_t)s2 * C + lane]);
                const float v3 = bf2f(xbf[(size_t)s3 * C + lane]);
                acc += (v0 + v1) + (v2 + v3);
            }
            for (; j < m; ++j)
                acc += bf2f(xbf[(size_t)__shfl(sid, j) * C + lane]);
        }
        const float inv = 1.0f / fmaxf((float)(end - beg), 1.0f);
        aggs[w * 4 + i][lane] = f2bf(acc * inv);
    }
    __syncthreads();

    // ---- phase 2: MFMA epilogue (wave w = channel tile w) ----
    const int r = lane & 15;
    const int q = lane >> 4;

    const bf16x8 bw0 = *(const bf16x8*)&wpack[(0*8 + 0*4 + w) * 64 + lane];
    const bf16x8 bw1 = *(const bf16x8*)&wpack[(0*8 + 1*4 + w) * 64 + lane];
    const bf16x8 br0 = *(const bf16x8*)&wpack[(1*8 + 0*4 + w) * 64 + lane];
    const bf16x8 br1 = *(const bf16x8*)&wpack[(1*8 + 1*4 + w) * 64 + lane];
    const float  bb  = bias[w * 16 + r];

    const unsigned short* rx = xbf + (size_t)(tileBase + r) * C;
    const bf16x8 a0 = *(const bf16x8*)&aggs[r][q * 8];
    const bf16x8 a1 = *(const bf16x8*)&aggs[r][32 + q * 8];
    const bf16x8 a2 = *(const bf16x8*)(rx + q * 8);
    const bf16x8 a3 = *(const bf16x8*)(rx + 32 + q * 8);

    f32x4 acc4 = {0.f, 0.f, 0.f, 0.f};
    acc4 = __builtin_amdgcn_mfma_f32_16x16x32_bf16(a0, bw0, acc4, 0, 0, 0);
    acc4 = __builtin_amdgcn_mfma_f32_16x16x32_bf16(a1, bw1, acc4, 0, 0, 0);
    acc4 = __builtin_amdgcn_mfma_f32_16x16x32_bf16(a2, br0, acc4, 0, 0, 0);
    acc4 = __builtin_amdgcn_mfma_f32_16x16x32_bf16(a3, br1, acc4, 0, 0, 0);

    #pragma unroll
    for (int i = 0; i < 4; ++i) {
        const int node = tileBase + q * 4 + i;
        out[(size_t)node * C + w * 16 + r] = fmaxf(acc4[i] + bb, 0.f);
    }
}

// ---------------------------------------------------------------------------
// Launch. ws layout (16B-aligned):
//   xbf          : ushort[3,200,000]   6.4 MB
//   wpack        : uint4[1024]         16 KB
//   bucketCursor : int[256]
//   rowptr       : int[50,008]
//   ebuf         : int[800,000]        3.2 MB
//   bucketbuf    : int[196*6144]       4.8 MB     total ~14.6 MB
// ---------------------------------------------------------------------------
extern "C" void kernel_launch(void* const* d_in, const int* in_sizes, int n_in,
                              void* d_out, int out_size, void* d_ws, size_t ws_size,
                              hipStream_t stream)
{
    const float* x    = (const float*)d_in[0];
    const int*   ei   = (const int*)d_in[1];
    // d_in[2] = edge_attr: drops out for kernel_size=1 SplineConv
    const float* W    = (const float*)d_in[3];
    const float* R    = (const float*)d_in[4];
    const float* bias = (const float*)d_in[5];

    char* wsb = (char*)d_ws;
    unsigned short* xbf = (unsigned short*)wsb;
    size_t off = (size_t)N_NODES * C * sizeof(unsigned short);
    uint4* wpack        = (uint4*)(wsb + off);  off += 1024 * sizeof(uint4);
    int*   bucketCursor = (int*)(wsb + off);    off += 256 * sizeof(int);
    int*   rowptr       = (int*)(wsb + off);    off += ((N_NODES + 8) & ~3) * sizeof(int);
    int*   ebuf         = (int*)(wsb + off);    off += (size_t)N_EDGES * sizeof(int);
    int*   bucketbuf    = (int*)(wsb + off);
    float* out          = (float*)d_out;

    zero_cursor   <<<1, 256, 0, stream>>>(bucketCursor);
    prep_bin      <<<PB_BLOCKS, 256, 0, stream>>>(x, W, R, ei, xbf, wpack,
                                                  bucketCursor, bucketbuf);
    csr_place_scan<<<NBUCK, 256, 0, stream>>>(bucketCursor, bucketbuf, rowptr, ebuf);
    agg_mfma      <<<NAGG, 256, 0, stream>>>(rowptr, ebuf, xbf, wpack, bias, out);
}

// Round 8
// 71.421 us; speedup vs baseline: 11.0784x; 1.0199x over previous
//
#include <hip/hip_runtime.h>

#define N_NODES 50000
#define N_EDGES 800000
#define C 64                          // channels (C_IN == C_HID == 64)
// edge binning
#define BUCKET_NODES 256
#define NBUCK ((N_NODES + BUCKET_NODES - 1) / BUCKET_NODES)  // 196
#define BUCKET_CAP 6144               // mean 4096, +32 sigma (proven on this graph)
#define BIN_CHUNK 8192
#define NBIN_BLOCKS ((N_EDGES + BIN_CHUNK - 1) / BIN_CHUNK)  // 98
#define PREP_XBLOCKS 199
#define PB_BLOCKS (1 + PREP_XBLOCKS + NBIN_BLOCKS)           // 298
// fused aggregate+mfma
#define AGG_NODES 16
#define NAGG (N_NODES / AGG_NODES)    // 3125 exactly (no tail)
#define LDSTR 72                      // LDS row stride in shorts (144 B = 9*16: 16B-aligned rows)

typedef __attribute__((ext_vector_type(8))) short bf16x8;
typedef __attribute__((ext_vector_type(4))) float f32x4;

__device__ inline unsigned short f2bf(float f) {          // round-to-nearest-even
    union { float f; unsigned u; } v; v.f = f;
    unsigned r = v.u + 0x7FFF + ((v.u >> 16) & 1);
    return (unsigned short)(r >> 16);
}
__device__ inline float bf2f(unsigned short h) {
    union { unsigned u; float f; } v; v.u = (unsigned)h << 16;
    return v.f;
}

// ---------------------------------------------------------------------------
// Kernel 0: zero the 256-int bucket cursor (cheap dispatch, graph-friendly).
// ---------------------------------------------------------------------------
__global__ __launch_bounds__(256) void zero_cursor(int* __restrict__ c)
{
    c[threadIdx.x] = 0;
}

// ---------------------------------------------------------------------------
// Kernel 1 (fused, role-split by blockIdx):
//   block 0            : pack W,root into bf16 MFMA B-fragments
//   blocks 1..199      : convert x -> bf16 row-major
//   blocks 200..297    : bin edges by dst>>8 (entry = (src<<8)|(dst&255))
// B-frag layout for mfma_f32_16x16x32_bf16: lane l holds
//   B[k = ks*32 + (l>>4)*8 + j][col = ct*16 + (l&15)], j=0..7.
// wpack slot s = f*64 + lane, f = mat*8 + ks*4 + ct  (mat 0=W, 1=root).
// ---------------------------------------------------------------------------
__global__ __launch_bounds__(256) void prep_bin(
    const float* __restrict__ x,
    const float* __restrict__ W,
    const float* __restrict__ R,
    const int*   __restrict__ ei,
    unsigned short* __restrict__ xbf,
    uint4* __restrict__ wpack,
    int* __restrict__ bucketCursor,
    int* __restrict__ bucketbuf)
{
    const int bid = blockIdx.x;

    if (bid == 0) {
        // ---- weight-pack role ----
        for (int s = threadIdx.x; s < 1024; s += 256) {
            const int f    = s >> 6;
            const int lane = s & 63;
            const int mat  = f >> 3, ks = (f >> 2) & 1, ct = f & 3;
            const float* src = mat ? R : W;
            const int kbase = ks * 32 + (lane >> 4) * 8;
            const int col   = ct * 16 + (lane & 15);
            unsigned wd[4];
            #pragma unroll
            for (int jj = 0; jj < 4; ++jj) {
                const unsigned lo16 = f2bf(src[(kbase + 2*jj    ) * C + col]);
                const unsigned hi16 = f2bf(src[(kbase + 2*jj + 1) * C + col]);
                wd[jj] = lo16 | (hi16 << 16);
            }
            uint4 o; o.x = wd[0]; o.y = wd[1]; o.z = wd[2]; o.w = wd[3];
            wpack[s] = o;
        }
        return;
    }

    if (bid <= PREP_XBLOCKS) {
        // ---- x-convert role ----
        const int nthreads = PREP_XBLOCKS * 256;
        const int total4 = (N_NODES * C) / 4;             // 800000 float4
        for (int i = (bid - 1) * 256 + threadIdx.x; i < total4; i += nthreads) {
            const float4 v = ((const float4*)x)[i];
            ushort4 o;
            o.x = f2bf(v.x); o.y = f2bf(v.y); o.z = f2bf(v.z); o.w = f2bf(v.w);
            ((ushort4*)xbf)[i] = o;
        }
        return;
    }

    // ---- edge-bin role (dst staged in LDS to avoid HBM re-read) ----
    __shared__ int sdst[BIN_CHUNK];                       // 32 KB
    __shared__ int cnt[NBUCK], cnt2[NBUCK], gb[NBUCK];
    for (int i = threadIdx.x; i < NBUCK; i += 256) { cnt[i] = 0; cnt2[i] = 0; }
    __syncthreads();

    const int bb = bid - 1 - PREP_XBLOCKS;
    const int e0 = bb * BIN_CHUNK;
    const int e1 = min(e0 + BIN_CHUNK, N_EDGES);
    const int ne = e1 - e0;

    for (int k = threadIdx.x; k < ne; k += 256) {
        const int d = ei[N_EDGES + e0 + k];
        sdst[k] = d;
        atomicAdd(&cnt[((unsigned)d) >> 8], 1);
    }
    __syncthreads();

    for (int i = threadIdx.x; i < NBUCK; i += 256)
        gb[i] = atomicAdd(&bucketCursor[i], cnt[i]);
    __syncthreads();

    for (int k = threadIdx.x; k < ne; k += 256) {
        const int src = ei[e0 + k];
        const int dst = sdst[k];
        const int bkt = ((unsigned)dst) >> 8;
        const int off = gb[bkt] + atomicAdd(&cnt2[bkt], 1);
        bucketbuf[bkt * BUCKET_CAP + off] = (src << 8) | (dst & 255);
    }
}

// ---------------------------------------------------------------------------
// Kernel 2: per-bucket {stage entries, LDS degree-hist, block scan, rowptr
// write, CSR placement} — all fused. Bucket offset derived in-block by
// wave 0 scanning bucketCursor (196 ints, L2-hot).
// ---------------------------------------------------------------------------
__global__ __launch_bounds__(256) void csr_place_scan(
    const int* __restrict__ bucketCursor,
    const int* __restrict__ bucketbuf,
    int* __restrict__ rowptr,
    int* __restrict__ ebuf)
{
    __shared__ int entries[BUCKET_CAP];                   // 24 KB
    __shared__ int lcur[BUCKET_NODES];
    __shared__ int wsum[4];
    __shared__ int boffS;

    const int b    = blockIdx.x;
    const int tid  = threadIdx.x;
    const int lane = tid & 63, w = tid >> 6;
    const int lo   = b * BUCKET_NODES;
    const int nn   = min(BUCKET_NODES, N_NODES - lo);
    const int cnt  = bucketCursor[b];

    if (w == 0) {                                         // bucket-offset scan
        const int base = lane * 4;
        int s0 = (base+0 < NBUCK) ? bucketCursor[base+0] : 0;
        int s1 = (base+1 < NBUCK) ? bucketCursor[base+1] : 0;
        int s2 = (base+2 < NBUCK) ? bucketCursor[base+2] : 0;
        int s3 = (base+3 < NBUCK) ? bucketCursor[base+3] : 0;
        const int tot = s0 + s1 + s2 + s3;
        int incl = tot;
        #pragma unroll
        for (int off = 1; off < 64; off <<= 1) {
            const int t = __shfl_up(incl, off);
            if (lane >= off) incl += t;
        }
        if (lane == (b >> 2)) {
            int v = incl - tot;
            if ((b & 3) > 0) v += s0;
            if ((b & 3) > 1) v += s1;
            if ((b & 3) > 2) v += s2;
            boffS = v;
        }
    }

    lcur[tid] = 0;
    for (int k = tid; k < cnt; k += 256) entries[k] = bucketbuf[b * BUCKET_CAP + k];
    __syncthreads();

    for (int k = tid; k < cnt; k += 256)
        atomicAdd(&lcur[entries[k] & 255], 1);            // LDS degree hist
    __syncthreads();

    const int v = (tid < nn) ? lcur[tid] : 0;
    int incl = v;                                         // block exclusive scan
    #pragma unroll
    for (int off = 1; off < 64; off <<= 1) {
        const int t = __shfl_up(incl, off);
        if (lane >= off) incl += t;
    }
    if (lane == 63) wsum[w] = incl;
    __syncthreads();
    int woff = boffS;
    for (int k = 0; k < 4; ++k) if (k < w) woff += wsum[k];
    const int excl = woff + incl - v;
    __syncthreads();                                      // all v-reads done
    if (tid < nn) {
        rowptr[lo + tid] = excl;
        lcur[tid] = excl;
        if (lo + tid == N_NODES - 1) rowptr[N_NODES] = excl + v;
    }
    __syncthreads();

    for (int k = tid; k < cnt; k += 256) {                // placement
        const int p   = entries[k];
        const int pos = atomicAdd(&lcur[p & 255], 1);
        ebuf[pos] = p >> 8;
    }
}

// ---------------------------------------------------------------------------
// Kernel 3 (fused): aggregate x (mean over incoming edges) into an LDS tile,
// then epilogue GEMM via MFMA:  out = relu( aggx @ W + x @ root + bias ).
// Block = 16 nodes (50000 = 3125*16, no tail), 4 waves.
//  Phase 1: wave w aggregates nodes w*4..w*4+3. WIDE GATHER: 4 lane-groups of
//    16; group g takes edge j+g, lane r loads uint2 = 4 bf16 channels
//    [4r,4r+4) of that edge's row -> ONE VMEM instr moves 4 rows (512 B).
//    Cross-group shfl_xor(16,32) reduce, then bf16-pack to LDS.
//  Phase 2: wave w owns channel tile w; A-frags: aggx from LDS, x from
//    global. D layout: col=lane&15 (channel), row=(lane>>4)*4+reg (node).
// ---------------------------------------------------------------------------
__global__ __launch_bounds__(256) void agg_mfma(
    const int* __restrict__ rowptr,
    const int* __restrict__ ebuf,
    const unsigned short* __restrict__ xbf,
    const uint4*  __restrict__ wpack,
    const float*  __restrict__ bias,
    float* __restrict__ out)
{
    __shared__ unsigned short aggs[AGG_NODES][LDSTR];

    const int lane = threadIdx.x & 63;
    const int w    = threadIdx.x >> 6;
    const int tileBase = (int)blockIdx.x * AGG_NODES;

    const int r = lane & 15;      // channel-quad id: channels [4r, 4r+4)
    const int g = lane >> 4;      // edge-group id 0..3

    // ---- phase 1: aggregation (4 nodes per wave) ----
    #pragma unroll
    for (int i = 0; i < 4; ++i) {
        const int n   = tileBase + w * 4 + i;
        const int beg = rowptr[n];
        const int end = rowptr[n + 1];
        float a0 = 0.f, a1 = 0.f, a2 = 0.f, a3 = 0.f;
        for (int base = beg; base < end; base += 64) {
            const int m = min(64, end - base);
            const int sid = (base + lane < end) ? ebuf[base + lane] : 0;
            for (int j = 0; j < m; j += 4) {
                const int  e     = j + g;
                const bool valid = e < m;
                const int  s     = __shfl(sid, valid ? e : 0);
                const uint2 v = *(const uint2*)(xbf + (size_t)s * C + r * 4);
                if (valid) {
                    a0 += bf2f((unsigned short)(v.x & 0xffff));
                    a1 += bf2f((unsigned short)(v.x >> 16));
                    a2 += bf2f((unsigned short)(v.y & 0xffff));
                    a3 += bf2f((unsigned short)(v.y >> 16));
                }
            }
        }
        // cross-group reduce: sum the 4 edge-groups' partials per channel
        #pragma unroll
        for (int off = 16; off <= 32; off <<= 1) {
            a0 += __shfl_xor(a0, off);
            a1 += __shfl_xor(a1, off);
            a2 += __shfl_xor(a2, off);
            a3 += __shfl_xor(a3, off);
        }
        if (g == 0) {
            const float inv = 1.0f / fmaxf((float)(end - beg), 1.0f);
            uint2 pv;
            pv.x = (unsigned)f2bf(a0 * inv) | ((unsigned)f2bf(a1 * inv) << 16);
            pv.y = (unsigned)f2bf(a2 * inv) | ((unsigned)f2bf(a3 * inv) << 16);
            *(uint2*)&aggs[w * 4 + i][r * 4] = pv;
        }
    }
    __syncthreads();

    // ---- phase 2: MFMA epilogue (wave w = channel tile w) ----
    const int q = lane >> 4;

    const bf16x8 bw0 = *(const bf16x8*)&wpack[(0*8 + 0*4 + w) * 64 + lane];
    const bf16x8 bw1 = *(const bf16x8*)&wpack[(0*8 + 1*4 + w) * 64 + lane];
    const bf16x8 br0 = *(const bf16x8*)&wpack[(1*8 + 0*4 + w) * 64 + lane];
    const bf16x8 br1 = *(const bf16x8*)&wpack[(1*8 + 1*4 + w) * 64 + lane];
    const float  bb  = bias[w * 16 + r];

    const unsigned short* rx = xbf + (size_t)(tileBase + r) * C;
    const bf16x8 a0 = *(const bf16x8*)&aggs[r][q * 8];
    const bf16x8 a1 = *(const bf16x8*)&aggs[r][32 + q * 8];
    const bf16x8 a2 = *(const bf16x8*)(rx + q * 8);
    const bf16x8 a3 = *(const bf16x8*)(rx + 32 + q * 8);

    f32x4 acc4 = {0.f, 0.f, 0.f, 0.f};
    acc4 = __builtin_amdgcn_mfma_f32_16x16x32_bf16(a0, bw0, acc4, 0, 0, 0);
    acc4 = __builtin_amdgcn_mfma_f32_16x16x32_bf16(a1, bw1, acc4, 0, 0, 0);
    acc4 = __builtin_amdgcn_mfma_f32_16x16x32_bf16(a2, br0, acc4, 0, 0, 0);
    acc4 = __builtin_amdgcn_mfma_f32_16x16x32_bf16(a3, br1, acc4, 0, 0, 0);

    #pragma unroll
    for (int i = 0; i < 4; ++i) {
        const int node = tileBase + q * 4 + i;
        out[(size_t)node * C + w * 16 + r] = fmaxf(acc4[i] + bb, 0.f);
    }
}

// ---------------------------------------------------------------------------
// Launch. ws layout (16B-aligned):
//   xbf          : ushort[3,200,000]   6.4 MB
//   wpack        : uint4[1024]         16 KB
//   bucketCursor : int[256]
//   rowptr       : int[50,008]
//   ebuf         : int[800,000]        3.2 MB
//   bucketbuf    : int[196*6144]       4.8 MB     total ~14.6 MB
// ---------------------------------------------------------------------------
extern "C" void kernel_launch(void* const* d_in, const int* in_sizes, int n_in,
                              void* d_out, int out_size, void* d_ws, size_t ws_size,
                              hipStream_t stream)
{
    const float* x    = (const float*)d_in[0];
    const int*   ei   = (const int*)d_in[1];
    // d_in[2] = edge_attr: drops out for kernel_size=1 SplineConv
    const float* W    = (const float*)d_in[3];
    const float* R    = (const float*)d_in[4];
    const float* bias = (const float*)d_in[5];

    char* wsb = (char*)d_ws;
    unsigned short* xbf = (unsigned short*)wsb;
    size_t off = (size_t)N_NODES * C * sizeof(unsigned short);
    uint4* wpack        = (uint4*)(wsb + off);  off += 1024 * sizeof(uint4);
    int*   bucketCursor = (int*)(wsb + off);    off += 256 * sizeof(int);
    int*   rowptr       = (int*)(wsb + off);    off += ((N_NODES + 8) & ~3) * sizeof(int);
    int*   ebuf         = (int*)(wsb + off);    off += (size_t)N_EDGES * sizeof(int);
    int*   bucketbuf    = (int*)(wsb + off);
    float* out          = (float*)d_out;

    zero_cursor   <<<1, 256, 0, stream>>>(bucketCursor);
    prep_bin      <<<PB_BLOCKS, 256, 0, stream>>>(x, W, R, ei, xbf, wpack,
                                                  bucketCursor, bucketbuf);
    csr_place_scan<<<NBUCK, 256, 0, stream>>>(bucketCursor, bucketbuf, rowptr, ebuf);
    agg_mfma      <<<NAGG, 256, 0, stream>>>(rowptr, ebuf, xbf, wpack, bias, out);
}